// Round 1
// baseline (267.947 us; speedup 1.0000x reference)
//
#include <hip/hip_runtime.h>
#include <hip/hip_bf16.h>
#include <math.h>

constexpr int CC  = 128;   // channels
constexpr int NH  = 8;     // heads
constexpr int KD  = 16;    // key dim
constexpr int BB  = 8;     // batch
constexpr int HH  = 32;
constexpr int WWW = 32;
constexpr int NN  = 1024;  // H*W
constexpr int BHW = BB * NN;  // elements per channel = 8192

// ---------------- K1: BN stats -> fused scale/shift ----------------
__global__ __launch_bounds__(256) void k_bnstats(const float* __restrict__ x,
                                                 const float* __restrict__ gamma,
                                                 const float* __restrict__ beta,
                                                 float* __restrict__ ss /* [2*128] */) {
    int c = blockIdx.x;
    int t = threadIdx.x;
    float s1 = 0.f, s2 = 0.f;
    for (int k = 0; k < BHW / 256; ++k) {
        int e = t + 256 * k;
        int b = e >> 10, i = e & 1023;
        float v = x[(size_t)b * (CC * NN) + (size_t)c * NN + i];
        s1 += v;
        s2 += v * v;
    }
    #pragma unroll
    for (int off = 32; off >= 1; off >>= 1) {
        s1 += __shfl_xor(s1, off);
        s2 += __shfl_xor(s2, off);
    }
    __shared__ float r1[4], r2[4];
    int wid = t >> 6, lane = t & 63;
    if (lane == 0) { r1[wid] = s1; r2[wid] = s2; }
    __syncthreads();
    if (t == 0) {
        float a1 = r1[0] + r1[1] + r1[2] + r1[3];
        float a2 = r2[0] + r2[1] + r2[2] + r2[3];
        float mean = a1 / (float)BHW;
        float var  = a2 / (float)BHW - mean * mean;
        float rstd = rsqrtf(var + 1e-5f);
        float sc = rstd * gamma[c];
        ss[c]      = sc;
        ss[CC + c] = beta[c] - mean * sc;
    }
}

// ---------------- K2: BN apply + exact GELU ----------------
__global__ __launch_bounds__(256) void k_act(const float* __restrict__ x,
                                             const float* __restrict__ ss,
                                             float* __restrict__ a) {
    int idx0 = blockIdx.x * 1024 + threadIdx.x;
    #pragma unroll
    for (int k = 0; k < 4; ++k) {
        int idx = idx0 + k * 256;
        int c = (idx >> 10) & 127;
        float v = x[idx] * ss[c] + ss[CC + c];
        a[idx] = 0.5f * v * (1.0f + erff(v * 0.70710678118654752f));
    }
}

// ---------------- K3: QKV projection GEMM ----------------
// grid: x = i-tile (16), y = proj*2 + o-tile (6), z = batch (8)
__global__ __launch_bounds__(256) void k_proj(const float* __restrict__ a,
                                              const float* __restrict__ wq,
                                              const float* __restrict__ wk,
                                              const float* __restrict__ wv,
                                              float* __restrict__ qkv) {
    int it = blockIdx.x, y = blockIdx.y, b = blockIdx.z;
    int p = y >> 1, ot = y & 1;
    int i0 = it * 64, o0 = ot * 64;
    const float* w = (p == 0) ? wq : (p == 1) ? wk : wv;

    __shared__ float wT[128][68];  // [c][o], transposed for float4 reads over o
    __shared__ float aS[128][68];  // [c][i]
    int t = threadIdx.x;
    #pragma unroll
    for (int k = 0; k < 32; ++k) {
        int idx = t + 256 * k;
        {
            int c = idx & 127, o = idx >> 7;
            wT[c][o] = w[(size_t)(o0 + o) * CC + c];
        }
        {
            int ii = idx & 63, c = idx >> 6;
            aS[c][ii] = a[(size_t)b * (CC * NN) + (size_t)c * NN + i0 + ii];
        }
    }
    __syncthreads();

    int to = t >> 4, ti = t & 15;
    float acc[4][4];
    #pragma unroll
    for (int u = 0; u < 4; ++u)
        #pragma unroll
        for (int v = 0; v < 4; ++v) acc[u][v] = 0.f;

    #pragma unroll 8
    for (int c = 0; c < 128; ++c) {
        float4 w4 = *(const float4*)&wT[c][to * 4];
        float4 a4 = *(const float4*)&aS[c][ti * 4];
        acc[0][0] = fmaf(w4.x, a4.x, acc[0][0]);
        acc[0][1] = fmaf(w4.x, a4.y, acc[0][1]);
        acc[0][2] = fmaf(w4.x, a4.z, acc[0][2]);
        acc[0][3] = fmaf(w4.x, a4.w, acc[0][3]);
        acc[1][0] = fmaf(w4.y, a4.x, acc[1][0]);
        acc[1][1] = fmaf(w4.y, a4.y, acc[1][1]);
        acc[1][2] = fmaf(w4.y, a4.z, acc[1][2]);
        acc[1][3] = fmaf(w4.y, a4.w, acc[1][3]);
        acc[2][0] = fmaf(w4.z, a4.x, acc[2][0]);
        acc[2][1] = fmaf(w4.z, a4.y, acc[2][1]);
        acc[2][2] = fmaf(w4.z, a4.z, acc[2][2]);
        acc[2][3] = fmaf(w4.z, a4.w, acc[2][3]);
        acc[3][0] = fmaf(w4.w, a4.x, acc[3][0]);
        acc[3][1] = fmaf(w4.w, a4.y, acc[3][1]);
        acc[3][2] = fmaf(w4.w, a4.z, acc[3][2]);
        acc[3][3] = fmaf(w4.w, a4.w, acc[3][3]);
    }

    float sc = (p == 0) ? 0.25f : 1.0f;  // q pre-scaled by 1/sqrt(16)
    #pragma unroll
    for (int u = 0; u < 4; ++u) {
        float4 r;
        r.x = acc[u][0] * sc;
        r.y = acc[u][1] * sc;
        r.z = acc[u][2] * sc;
        r.w = acc[u][3] * sc;
        *(float4*)&qkv[(size_t)p * (BB * CC * NN) + (size_t)b * (CC * NN) +
                       (size_t)(o0 + to * 4 + u) * NN + i0 + ti * 4] = r;
    }
}

// ---------------- K4: attention (full-row softmax, K/V head in LDS) ----------------
// grid: x = b*8+h (64), y = query chunk (4 x 256 queries). block = 512 (8 waves)
__global__ __launch_bounds__(512) void k_attn(const float* __restrict__ qkv,
                                              const float* __restrict__ x,
                                              const float* __restrict__ peh,
                                              const float* __restrict__ pew,
                                              float* __restrict__ out) {
    __shared__ float Ks[16][1024];     // 64 KB
    __shared__ float Vs[16][1024];     // 64 KB
    __shared__ float oOut[16][260];    // 16.6 KB staging for coalesced store
    __shared__ float oS[8][16][17];    // per-wave transpose-reduce scratch
    __shared__ float phS[64], pwS[64];

    int bh = blockIdx.x;
    int b = bh >> 3, h = bh & 7;
    int qbase = blockIdx.y * 256;
    int t = threadIdx.x;
    size_t headoff = (size_t)b * (CC * NN) + (size_t)h * KD * NN;
    const float* qg = qkv + headoff;
    const float* kg = qkv + (size_t)(BB * CC * NN) + headoff;
    const float* vg = qkv + (size_t)(2 * BB * CC * NN) + headoff;

    #pragma unroll
    for (int k = 0; k < 32; ++k) {
        int idx = t + 512 * k;
        int d = idx >> 10, j = idx & 1023;
        Ks[d][j] = kg[(size_t)d * NN + j];
        Vs[d][j] = vg[(size_t)d * NN + j];
    }
    if (t < 63) { phS[t] = peh[t]; pwS[t] = pew[t]; }
    __syncthreads();

    int wid = t >> 6, lane = t & 63;
    int hjl = lane >> 5;   // row-part of this lane's base j
    int wj  = lane & 31;   // col-part of this lane's j (constant over mm)

    #pragma unroll 1
    for (int u = 0; u < 16; ++u) {
        int il0 = wid * 32 + 2 * u;
        int i0g = qbase + il0;           // query pair (i0g, i0g+1); same hi
        int hi  = i0g >> 5;
        int wi0 = i0g & 31;              // even, so wi0+1 stays in row

        float q0[16], q1[16];
        #pragma unroll
        for (int d = 0; d < 16; ++d) {
            q0[d] = qg[(size_t)d * NN + i0g];
            q1[d] = qg[(size_t)d * NN + i0g + 1];
        }
        float pw0 = pwS[wi0 + 31 - wj];
        float pw1 = pwS[wi0 + 32 - wj];
        int phbase = hi + 31 - hjl;

        float s0[16], s1[16];
        #pragma unroll
        for (int mm = 0; mm < 16; ++mm) {
            float a0 = 0.f, a1 = 0.f;
            #pragma unroll
            for (int d = 0; d < 16; ++d) {
                float kv = Ks[d][lane + 64 * mm];
                a0 = fmaf(q0[d], kv, a0);
                a1 = fmaf(q1[d], kv, a1);
            }
            float ph = phS[phbase - 2 * mm];
            s0[mm] = a0 + ph + pw0;
            s1[mm] = a1 + ph + pw1;
        }

        // softmax over 1024 (16 per lane x 64 lanes)
        float m0 = s0[0], m1 = s1[0];
        #pragma unroll
        for (int mm = 1; mm < 16; ++mm) {
            m0 = fmaxf(m0, s0[mm]);
            m1 = fmaxf(m1, s1[mm]);
        }
        #pragma unroll
        for (int off = 32; off >= 1; off >>= 1) {
            m0 = fmaxf(m0, __shfl_xor(m0, off));
            m1 = fmaxf(m1, __shfl_xor(m1, off));
        }
        float sum0 = 0.f, sum1 = 0.f;
        #pragma unroll
        for (int mm = 0; mm < 16; ++mm) {
            s0[mm] = __expf(s0[mm] - m0);
            s1[mm] = __expf(s1[mm] - m1);
            sum0 += s0[mm];
            sum1 += s1[mm];
        }
        #pragma unroll
        for (int off = 32; off >= 1; off >>= 1) {
            sum0 += __shfl_xor(sum0, off);
            sum1 += __shfl_xor(sum1, off);
        }
        float r0 = 1.0f / sum0, r1 = 1.0f / sum1;
        #pragma unroll
        for (int mm = 0; mm < 16; ++mm) { s0[mm] *= r0; s1[mm] *= r1; }

        // PV
        float o0[16], o1[16];
        #pragma unroll
        for (int d = 0; d < 16; ++d) { o0[d] = 0.f; o1[d] = 0.f; }
        #pragma unroll
        for (int mm = 0; mm < 16; ++mm) {
            #pragma unroll
            for (int d = 0; d < 16; ++d) {
                float vv = Vs[d][lane + 64 * mm];
                o0[d] = fmaf(s0[mm], vv, o0[d]);
                o1[d] = fmaf(s1[mm], vv, o1[d]);
            }
        }

        // stage A: fold 64 lanes -> 16 lane-groups
        #pragma unroll
        for (int d = 0; d < 16; ++d) {
            o0[d] += __shfl_xor(o0[d], 16);
            o0[d] += __shfl_xor(o0[d], 32);
            o1[d] += __shfl_xor(o1[d], 16);
            o1[d] += __shfl_xor(o1[d], 32);
        }
        // stage B: LDS transpose-reduce (16 x 16), query 0 then 1
        if (lane < 16) {
            #pragma unroll
            for (int d = 0; d < 16; ++d) oS[wid][lane][d] = o0[d];
            float acc = 0.f;
            #pragma unroll
            for (int g = 0; g < 16; ++g) acc += oS[wid][g][lane];
            oOut[lane][il0] = acc;
            #pragma unroll
            for (int d = 0; d < 16; ++d) oS[wid][lane][d] = o1[d];
            float acc1 = 0.f;
            #pragma unroll
            for (int g = 0; g < 16; ++g) acc1 += oS[wid][g][lane];
            oOut[lane][il0 + 1] = acc1;
        }
    }
    __syncthreads();

    // coalesced residual store: 16 d-rows x 256 queries
    #pragma unroll
    for (int k = 0; k < 8; ++k) {
        int idx = t + 512 * k;
        int d = idx >> 8, ii = idx & 255;
        size_t go = headoff + (size_t)d * NN + qbase + ii;
        out[go] = x[go] + oOut[d][ii];
    }
}

extern "C" void kernel_launch(void* const* d_in, const int* in_sizes, int n_in,
                              void* d_out, int out_size, void* d_ws, size_t ws_size,
                              hipStream_t stream) {
    const float* x     = (const float*)d_in[0];
    const float* gamma = (const float*)d_in[1];
    const float* beta  = (const float*)d_in[2];
    const float* wq    = (const float*)d_in[3];
    const float* wk    = (const float*)d_in[4];
    const float* wv    = (const float*)d_in[5];
    const float* peh   = (const float*)d_in[6];
    const float* pew   = (const float*)d_in[7];
    float* out = (float*)d_out;
    float* ws  = (float*)d_ws;

    float* ss  = ws;                     // 256 floats: scale/shift
    float* a   = ws + 256;               // 1,048,576 floats: activations [B,C,N]
    float* qkv = ws + 256 + BB * CC * NN; // 3 x 1,048,576 floats: q,k,v [B,C,N]

    k_bnstats<<<128, 256, 0, stream>>>(x, gamma, beta, ss);
    k_act<<<1024, 256, 0, stream>>>(x, ss, a);
    k_proj<<<dim3(16, 6, 8), 256, 0, stream>>>(a, wq, wk, wv, qkv);
    k_attn<<<dim3(64, 4), 512, 0, stream>>>(qkv, x, peh, pew, out);
}

// Round 2
// 69.751 us; speedup vs baseline: 3.8415x; 3.8415x over previous
//
#include <hip/hip_runtime.h>
#include <hip/hip_bf16.h>
#include <math.h>

typedef short bf4 __attribute__((ext_vector_type(4)));
typedef float f32x4 __attribute__((ext_vector_type(4)));

constexpr int CC  = 128;
constexpr int NH  = 8;
constexpr int KD  = 16;
constexpr int BB  = 8;
constexpr int NN  = 1024;
constexpr int BHW = BB * NN;
constexpr float LOG2E = 1.44269504088896340736f;

static __device__ __forceinline__ short f2bf(float x) {
    __hip_bfloat16 b = __float2bfloat16(x);
    short s;
    __builtin_memcpy(&s, &b, 2);
    return s;
}

static __device__ __forceinline__ f32x4 mfma16(bf4 a, bf4 b, f32x4 c) {
#if __has_builtin(__builtin_amdgcn_mfma_f32_16x16x16bf16_1k)
    return __builtin_amdgcn_mfma_f32_16x16x16bf16_1k(a, b, c, 0, 0, 0);
#else
    f32x4 d;
    asm volatile("v_mfma_f32_16x16x16_bf16 %0, %1, %2, %3"
                 : "=&v"(d) : "v"(a), "v"(b), "v"(c));
    return d;
#endif
}

// ---------------- K1: BN stats -> fused scale/shift ----------------
__global__ __launch_bounds__(256) void k_bnstats(const float* __restrict__ x,
                                                 const float* __restrict__ gamma,
                                                 const float* __restrict__ beta,
                                                 float* __restrict__ ss) {
    int c = blockIdx.x;
    int t = threadIdx.x;
    float s1 = 0.f, s2 = 0.f;
    for (int k = 0; k < BHW / 256; ++k) {
        int e = t + 256 * k;
        int b = e >> 10, i = e & 1023;
        float v = x[(size_t)b * (CC * NN) + (size_t)c * NN + i];
        s1 += v;
        s2 += v * v;
    }
    #pragma unroll
    for (int off = 32; off >= 1; off >>= 1) {
        s1 += __shfl_xor(s1, off);
        s2 += __shfl_xor(s2, off);
    }
    __shared__ float r1[4], r2[4];
    int wid = t >> 6, lane = t & 63;
    if (lane == 0) { r1[wid] = s1; r2[wid] = s2; }
    __syncthreads();
    if (t == 0) {
        float a1 = r1[0] + r1[1] + r1[2] + r1[3];
        float a2 = r2[0] + r2[1] + r2[2] + r2[3];
        float mean = a1 / (float)BHW;
        float var  = a2 / (float)BHW - mean * mean;
        float rstd = rsqrtf(var + 1e-5f);
        float sc = rstd * gamma[c];
        ss[c]      = sc;
        ss[CC + c] = beta[c] - mean * sc;
    }
}

// ---------------- K2: BN apply + exact GELU ----------------
__global__ __launch_bounds__(256) void k_act(const float* __restrict__ x,
                                             const float* __restrict__ ss,
                                             float* __restrict__ a) {
    int idx0 = blockIdx.x * 1024 + threadIdx.x;
    #pragma unroll
    for (int k = 0; k < 4; ++k) {
        int idx = idx0 + k * 256;
        int c = (idx >> 10) & 127;
        float v = x[idx] * ss[c] + ss[CC + c];
        a[idx] = 0.5f * v * (1.0f + erff(v * 0.70710678118654752f));
    }
}

// ---------------- K3: QKV projection GEMM -> bf16 MFMA fragment layouts ----
// Fragment layouts (16x16x16 bf16 MFMA, lane l = 0..63, hl=l>>4, li=l&15):
//  Qf[bh][it][l][jj] = qhat[d=4*hl+jj][i=it*16+li]   (B-frag: n=i, k=d)
//  Kf[bh][jt][l][jj] = k   [d=4*hl+jj][j=jt*16+li]   (A-frag: m=j, k=d)
//  Vf[bh][jc][l][jj] = v   [d=li     ][j=jc*16+4*hl+jj] (A-frag: m=d, k=j)
// qhat = q * (0.25 * log2 e)  (qk_scale and exp->exp2 folded in)
__global__ __launch_bounds__(256) void k_proj(const float* __restrict__ a,
                                              const float* __restrict__ wq,
                                              const float* __restrict__ wk,
                                              const float* __restrict__ wv,
                                              short* __restrict__ qf,
                                              short* __restrict__ kf,
                                              short* __restrict__ vf) {
    int it = blockIdx.x, y = blockIdx.y, b = blockIdx.z;
    int p = y >> 1, ot = y & 1;
    int i0 = it * 64, o0 = ot * 64;
    const float* w = (p == 0) ? wq : (p == 1) ? wk : wv;

    __shared__ float wT[128][68];
    __shared__ float aS[128][68];
    int t = threadIdx.x;
    #pragma unroll
    for (int k = 0; k < 32; ++k) {
        int idx = t + 256 * k;
        {
            int c = idx & 127, o = idx >> 7;
            wT[c][o] = w[(size_t)(o0 + o) * CC + c];
        }
        {
            int ii = idx & 63, c = idx >> 6;
            aS[c][ii] = a[(size_t)b * (CC * NN) + (size_t)c * NN + i0 + ii];
        }
    }
    __syncthreads();

    int to = t >> 4, ti = t & 15;
    float acc[4][4];
    #pragma unroll
    for (int u = 0; u < 4; ++u)
        #pragma unroll
        for (int v = 0; v < 4; ++v) acc[u][v] = 0.f;

    #pragma unroll 8
    for (int c = 0; c < 128; ++c) {
        float4 w4 = *(const float4*)&wT[c][to * 4];
        float4 a4 = *(const float4*)&aS[c][ti * 4];
        acc[0][0] = fmaf(w4.x, a4.x, acc[0][0]);
        acc[0][1] = fmaf(w4.x, a4.y, acc[0][1]);
        acc[0][2] = fmaf(w4.x, a4.z, acc[0][2]);
        acc[0][3] = fmaf(w4.x, a4.w, acc[0][3]);
        acc[1][0] = fmaf(w4.y, a4.x, acc[1][0]);
        acc[1][1] = fmaf(w4.y, a4.y, acc[1][1]);
        acc[1][2] = fmaf(w4.y, a4.z, acc[1][2]);
        acc[1][3] = fmaf(w4.y, a4.w, acc[1][3]);
        acc[2][0] = fmaf(w4.z, a4.x, acc[2][0]);
        acc[2][1] = fmaf(w4.z, a4.y, acc[2][1]);
        acc[2][2] = fmaf(w4.z, a4.z, acc[2][2]);
        acc[2][3] = fmaf(w4.z, a4.w, acc[2][3]);
        acc[3][0] = fmaf(w4.w, a4.x, acc[3][0]);
        acc[3][1] = fmaf(w4.w, a4.y, acc[3][1]);
        acc[3][2] = fmaf(w4.w, a4.z, acc[3][2]);
        acc[3][3] = fmaf(w4.w, a4.w, acc[3][3]);
    }

    float sc = (p == 0) ? 0.25f * LOG2E : 1.0f;
    #pragma unroll
    for (int u = 0; u < 4; ++u) {
        #pragma unroll
        for (int vv = 0; vv < 4; ++vv) {
            float val = acc[u][vv] * sc;
            int o = o0 + to * 4 + u;       // output channel
            int i = i0 + ti * 4 + vv;      // pixel
            int h = o >> 4, d = o & 15;
            size_t bh = (size_t)b * NH + h;
            short bv = f2bf(val);
            if (p < 2) {
                short* dst = (p == 0) ? qf : kf;
                dst[((bh * 64 + (i >> 4)) * 64 + (((d >> 2) << 4) | (i & 15))) * 4 + (d & 3)] = bv;
            } else {
                vf[((bh * 64 + (i >> 4)) * 64 + ((((i & 15) >> 2) << 4) | d)) * 4 + (i & 3)] = bv;
            }
        }
    }
}

// ---------------- K4: flash attention via MFMA -------------------------
// grid (64, 4): x = b*8+h, y = 256-query chunk. block = 256 (4 waves).
// Wave owns 64 queries (4 i-tiles). K-loop: 64-key chunks (4 j-tiles),
// double-buffered fragment prefetch from global.
__global__ __launch_bounds__(256, 2) void k_attn(const short* __restrict__ qf,
                                                 const short* __restrict__ kf,
                                                 const short* __restrict__ vf,
                                                 const float* __restrict__ x,
                                                 const float* __restrict__ peh,
                                                 const float* __restrict__ pew,
                                                 float* __restrict__ out) {
    __shared__ float phS[64], pwS[64];
    int t = threadIdx.x;
    if (t < 63) { phS[t] = peh[t] * LOG2E; pwS[t] = pew[t] * LOG2E; }
    __syncthreads();

    int bh = blockIdx.x;
    int qb16 = blockIdx.y * 16;
    int wid = t >> 6, lane = t & 63;
    int li = lane & 15, hl = lane >> 4;
    int it0 = qb16 + wid * 4;      // wave's first global i-tile (even)
    int hb = it0 >> 1;

    const short* qfh = qf + (size_t)bh * 64 * 256;
    const short* kfh = kf + (size_t)bh * 64 * 256;
    const short* vfh = vf + (size_t)bh * 64 * 256;

    // Q fragments (held all loop)
    bf4 qfr[4];
    #pragma unroll
    for (int u = 0; u < 4; ++u)
        qfr[u] = *(const bf4*)(qfh + ((size_t)(it0 + u) * 64 + lane) * 4);

    // w-bias: constant over the K loop. pw4[it&1][jt&1][r]
    f32x4 pw4[2][2];
    #pragma unroll
    for (int ip = 0; ip < 2; ++ip)
        #pragma unroll
        for (int jp = 0; jp < 2; ++jp)
            #pragma unroll
            for (int r = 0; r < 4; ++r) {
                int wi = (ip << 4) | li;
                int wj = (jp << 4) + 4 * hl + r;
                pw4[ip][jp][r] = pwS[wi + 31 - wj];
            }

    f32x4 oacc[4];
    float mrun[4], lrun[4];
    #pragma unroll
    for (int u = 0; u < 4; ++u) {
        oacc[u] = (f32x4)0.f;
        mrun[u] = -INFINITY;
        lrun[u] = 0.f;
    }

    auto loadf = [&](bf4* kb, bf4* vb, int ch) {
        const short* kp = kfh + (size_t)ch * 4 * 256;
        const short* vp = vfh + (size_t)ch * 4 * 256;
        #pragma unroll
        for (int jt = 0; jt < 4; ++jt) {
            kb[jt] = *(const bf4*)(kp + (jt * 64 + lane) * 4);
            vb[jt] = *(const bf4*)(vp + (jt * 64 + lane) * 4);
        }
    };

    auto compute = [&](bf4* kb, bf4* vb, int ch) {
        float phv[2][2];
        #pragma unroll
        for (int uh = 0; uh < 2; ++uh)
            #pragma unroll
            for (int jh = 0; jh < 2; ++jh)
                phv[uh][jh] = phS[hb + uh + 31 - 2 * ch - jh];
        #pragma unroll
        for (int u = 0; u < 4; ++u) {
            // S^T tiles: m=j (16), n=i (16); bias in the C operand
            f32x4 s[4];
            #pragma unroll
            for (int jt = 0; jt < 4; ++jt) {
                float ph = phv[u >> 1][jt >> 1];
                f32x4 c = pw4[u & 1][jt & 1];
                c[0] += ph; c[1] += ph; c[2] += ph; c[3] += ph;
                s[jt] = mfma16(kb[jt], qfr[u], c);
            }
            // row max over 16 in-lane + cross hl-groups
            float mc = fmaxf(fmaxf(fmaxf(s[0][0], s[0][1]), fmaxf(s[0][2], s[0][3])),
                             fmaxf(fmaxf(s[1][0], s[1][1]), fmaxf(s[1][2], s[1][3])));
            mc = fmaxf(mc, fmaxf(fmaxf(fmaxf(s[2][0], s[2][1]), fmaxf(s[2][2], s[2][3])),
                                 fmaxf(fmaxf(s[3][0], s[3][1]), fmaxf(s[3][2], s[3][3]))));
            mc = fmaxf(mc, __shfl_xor(mc, 16));
            mc = fmaxf(mc, __shfl_xor(mc, 32));
            float mnew = fmaxf(mrun[u], mc);
            float fac = exp2f(mrun[u] - mnew);
            mrun[u] = mnew;
            float ps = 0.f;
            #pragma unroll
            for (int jt = 0; jt < 4; ++jt)
                #pragma unroll
                for (int r = 0; r < 4; ++r) {
                    s[jt][r] = exp2f(s[jt][r] - mnew);
                    ps += s[jt][r];
                }
            ps += __shfl_xor(ps, 16);
            ps += __shfl_xor(ps, 32);
            lrun[u] = lrun[u] * fac + ps;
            #pragma unroll
            for (int r = 0; r < 4; ++r) oacc[u][r] *= fac;
            // PV: O'[d][i] += V * P  (P already in B-frag layout)
            #pragma unroll
            for (int jt = 0; jt < 4; ++jt) {
                bf4 pf;
                pf[0] = f2bf(s[jt][0]);
                pf[1] = f2bf(s[jt][1]);
                pf[2] = f2bf(s[jt][2]);
                pf[3] = f2bf(s[jt][3]);
                oacc[u] = mfma16(vb[jt], pf, oacc[u]);
            }
        }
    };

    bf4 kA[4], vA[4], kB[4], vB[4];
    loadf(kA, vA, 0);
    #pragma unroll 1
    for (int ch = 0; ch < 16; ch += 2) {
        loadf(kB, vB, ch + 1);
        compute(kA, vA, ch);
        if (ch + 2 < 16) loadf(kA, vA, ch + 2);
        compute(kB, vB, ch + 1);
    }

    // epilogue: out = x + O'/l   (O'[d=4*hl+r][i=it*16+li])
    int b = bh >> 3, h = bh & 7;
    size_t base = (size_t)b * (CC * NN) + (size_t)h * KD * NN;
    #pragma unroll
    for (int u = 0; u < 4; ++u) {
        float rl = 1.0f / lrun[u];
        int i = (it0 + u) * 16 + li;
        #pragma unroll
        for (int r = 0; r < 4; ++r) {
            int d = 4 * hl + r;
            size_t g = base + (size_t)d * NN + i;
            out[g] = x[g] + oacc[u][r] * rl;
        }
    }
}

extern "C" void kernel_launch(void* const* d_in, const int* in_sizes, int n_in,
                              void* d_out, int out_size, void* d_ws, size_t ws_size,
                              hipStream_t stream) {
    const float* x     = (const float*)d_in[0];
    const float* gamma = (const float*)d_in[1];
    const float* beta  = (const float*)d_in[2];
    const float* wq    = (const float*)d_in[3];
    const float* wk    = (const float*)d_in[4];
    const float* wv    = (const float*)d_in[5];
    const float* peh   = (const float*)d_in[6];
    const float* pew   = (const float*)d_in[7];
    float* out = (float*)d_out;
    float* ws  = (float*)d_ws;

    float* ss = ws;                                  // 256 f32
    float* a  = ws + 256;                            // 1M f32 activations
    short* qf = (short*)(ws + 256 + BB * CC * NN);   // 1M bf16 frags
    short* kf = qf + (1 << 20);
    short* vf = kf + (1 << 20);

    k_bnstats<<<128, 256, 0, stream>>>(x, gamma, beta, ss);
    k_act<<<1024, 256, 0, stream>>>(x, ss, a);
    k_proj<<<dim3(16, 6, 8), 256, 0, stream>>>(a, wq, wk, wv, qf, kf, vf);
    k_attn<<<dim3(64, 4), 256, 0, stream>>>(qf, kf, vf, x, peh, pew, out);
}

// Round 4
// 55.427 us; speedup vs baseline: 4.8342x; 1.2584x over previous
//
#include <hip/hip_runtime.h>
#include <hip/hip_bf16.h>
#include <math.h>

typedef short bf4 __attribute__((ext_vector_type(4)));
typedef float f32x4 __attribute__((ext_vector_type(4)));

constexpr int CC  = 128;
constexpr int NH  = 8;
constexpr int KD  = 16;
constexpr int BB  = 8;
constexpr int NN  = 1024;
constexpr int BHW = BB * NN;
constexpr float LOG2E = 1.44269504088896340736f;

static __device__ __forceinline__ short f2bf(float x) {
    __hip_bfloat16 b = __float2bfloat16(x);
    short s;
    __builtin_memcpy(&s, &b, 2);
    return s;
}
static __device__ __forceinline__ float bf2f(short s) {
    unsigned u = ((unsigned)(unsigned short)s) << 16;
    float f;
    __builtin_memcpy(&f, &u, 4);
    return f;
}
static __device__ __forceinline__ unsigned fbits(float x) {
    unsigned u;
    __builtin_memcpy(&u, &x, 4);
    return u;
}

static __device__ __forceinline__ f32x4 mfma16(bf4 a, bf4 b, f32x4 c) {
#if __has_builtin(__builtin_amdgcn_mfma_f32_16x16x16bf16_1k)
    return __builtin_amdgcn_mfma_f32_16x16x16bf16_1k(a, b, c, 0, 0, 0);
#else
    f32x4 d;
    asm volatile("v_mfma_f32_16x16x16_bf16 %0, %1, %2, %3"
                 : "=&v"(d) : "v"(a), "v"(b), "v"(c));
    return d;
#endif
}

// ---------------- K1: BN stats -> fused scale/shift ----------------
__global__ __launch_bounds__(256) void k_bnstats(const float* __restrict__ x,
                                                 const float* __restrict__ gamma,
                                                 const float* __restrict__ beta,
                                                 float* __restrict__ ss) {
    int c = blockIdx.x;
    int t = threadIdx.x;
    float s1 = 0.f, s2 = 0.f;
    #pragma unroll
    for (int k = 0; k < 8; ++k) {
        int e = t + 256 * k;           // f4 index within channel (2048 total)
        int b = e >> 8, off = e & 255; // 256 float4 per (b,c) row
        float4 v = ((const float4*)(x + ((size_t)b * CC + c) * NN))[off];
        s1 += v.x + v.y + v.z + v.w;
        s2 += v.x * v.x + v.y * v.y + v.z * v.z + v.w * v.w;
    }
    #pragma unroll
    for (int off = 32; off >= 1; off >>= 1) {
        s1 += __shfl_xor(s1, off);
        s2 += __shfl_xor(s2, off);
    }
    __shared__ float r1[4], r2[4];
    int wid = t >> 6, lane = t & 63;
    if (lane == 0) { r1[wid] = s1; r2[wid] = s2; }
    __syncthreads();
    if (t == 0) {
        float a1 = r1[0] + r1[1] + r1[2] + r1[3];
        float a2 = r2[0] + r2[1] + r2[2] + r2[3];
        float mean = a1 / (float)BHW;
        float var  = a2 / (float)BHW - mean * mean;
        float rstd = rsqrtf(var + 1e-5f);
        float sc = rstd * gamma[c];
        ss[c]      = sc;
        ss[CC + c] = beta[c] - mean * sc;
    }
}

// ---------------- K2: BN apply + exact GELU (float4) ----------------
// 256 blocks x 256 threads x 4 float4 = 1,048,576 floats total.
__global__ __launch_bounds__(256) void k_act(const float* __restrict__ x,
                                             const float* __restrict__ ss,
                                             float* __restrict__ a) {
    int e0 = blockIdx.x * 1024 + threadIdx.x;  // f4 index
    #pragma unroll
    for (int k = 0; k < 4; ++k) {
        int e = e0 + k * 256;
        int c = (e >> 8) & 127;
        float sc = ss[c], sh = ss[CC + c];
        float4 v = ((const float4*)x)[e];
        v.x = v.x * sc + sh; v.y = v.y * sc + sh;
        v.z = v.z * sc + sh; v.w = v.w * sc + sh;
        v.x = 0.5f * v.x * (1.0f + erff(v.x * 0.70710678f));
        v.y = 0.5f * v.y * (1.0f + erff(v.y * 0.70710678f));
        v.z = 0.5f * v.z * (1.0f + erff(v.z * 0.70710678f));
        v.w = 0.5f * v.w * (1.0f + erff(v.w * 0.70710678f));
        ((float4*)a)[e] = v;
    }
}

// ---------------- K3: QKV projection GEMM -> bf16 MFMA fragments ----
//  Qf[bh][it][l][jj] = qhat[d=4*hl+jj][i=it*16+li]   (B-frag)
//  Kf[bh][jt][l][jj] = k   [d=4*hl+jj][j=jt*16+li]   (A-frag)
//  Vf[bh][jc][l][jj] = v   [d=li     ][j=jc*16+4*hl+jj] (A-frag)
__global__ __launch_bounds__(256) void k_proj(const float* __restrict__ a,
                                              const float* __restrict__ wq,
                                              const float* __restrict__ wk,
                                              const float* __restrict__ wv,
                                              short* __restrict__ qf,
                                              short* __restrict__ kf,
                                              short* __restrict__ vf) {
    int it = blockIdx.x, y = blockIdx.y, b = blockIdx.z;
    int p = y >> 1, ot = y & 1;
    int i0 = it * 64, o0 = ot * 64;
    const float* w = (p == 0) ? wq : (p == 1) ? wk : wv;

    __shared__ float wT[128][68];
    __shared__ float aS[128][68];
    int t = threadIdx.x;
    #pragma unroll
    for (int k = 0; k < 32; ++k) {
        int idx = t + 256 * k;
        {
            int c = idx & 127, o = idx >> 7;
            wT[c][o] = w[(size_t)(o0 + o) * CC + c];
        }
        {
            int ii = idx & 63, c = idx >> 6;
            aS[c][ii] = a[(size_t)b * (CC * NN) + (size_t)c * NN + i0 + ii];
        }
    }
    __syncthreads();

    int to = t >> 4, ti = t & 15;
    float acc[4][4];
    #pragma unroll
    for (int u = 0; u < 4; ++u)
        #pragma unroll
        for (int v = 0; v < 4; ++v) acc[u][v] = 0.f;

    #pragma unroll 8
    for (int c = 0; c < 128; ++c) {
        float4 w4 = *(const float4*)&wT[c][to * 4];
        float4 a4 = *(const float4*)&aS[c][ti * 4];
        acc[0][0] = fmaf(w4.x, a4.x, acc[0][0]);
        acc[0][1] = fmaf(w4.x, a4.y, acc[0][1]);
        acc[0][2] = fmaf(w4.x, a4.z, acc[0][2]);
        acc[0][3] = fmaf(w4.x, a4.w, acc[0][3]);
        acc[1][0] = fmaf(w4.y, a4.x, acc[1][0]);
        acc[1][1] = fmaf(w4.y, a4.y, acc[1][1]);
        acc[1][2] = fmaf(w4.y, a4.z, acc[1][2]);
        acc[1][3] = fmaf(w4.y, a4.w, acc[1][3]);
        acc[2][0] = fmaf(w4.z, a4.x, acc[2][0]);
        acc[2][1] = fmaf(w4.z, a4.y, acc[2][1]);
        acc[2][2] = fmaf(w4.z, a4.z, acc[2][2]);
        acc[2][3] = fmaf(w4.z, a4.w, acc[2][3]);
        acc[3][0] = fmaf(w4.w, a4.x, acc[3][0]);
        acc[3][1] = fmaf(w4.w, a4.y, acc[3][1]);
        acc[3][2] = fmaf(w4.w, a4.z, acc[3][2]);
        acc[3][3] = fmaf(w4.w, a4.w, acc[3][3]);
    }

    float sc = (p == 0) ? 0.25f * LOG2E : 1.0f;
    int ob = o0 + to * 4;              // output-channel base (mult of 4)
    int h  = ob >> 4;                  // constant over u
    size_t bh = (size_t)b * NH + h;
    if (p < 2) {
        short* dst = (p == 0) ? qf : kf;
        int d2 = (ob & 15) >> 2;
        #pragma unroll
        for (int vv = 0; vv < 4; ++vv) {
            int i = i0 + ti * 4 + vv;
            bf4 r;
            #pragma unroll
            for (int u = 0; u < 4; ++u) r[u] = f2bf(acc[u][vv] * sc);
            *(bf4*)&dst[((bh * 64 + (i >> 4)) * 64 + ((d2 << 4) | (i & 15))) * 4] = r;
        }
    } else {
        int it4 = (i0 + ti * 4) >> 4;  // constant over vv
        int ii2 = ti & 3;
        #pragma unroll
        for (int u = 0; u < 4; ++u) {
            int d = (ob + u) & 15;
            bf4 r;
            #pragma unroll
            for (int vv = 0; vv < 4; ++vv) r[vv] = f2bf(acc[u][vv]);
            *(bf4*)&vf[((bh * 64 + it4) * 64 + ((ii2 << 4) | d)) * 4] = r;
        }
    }
}

// ---------------- K4: one-pass attention via Cauchy-Schwarz bound ------
// grid (64, 16): x = b*8+h, y = 4 i-tiles. block = 256 (4 waves), wave owns
// one 16-query i-tile. M_i = |q_i| * max_j|k_j| + max(bias) >= true row max,
// so softmax is one pass: P = exp2(s - M_i), l accumulated per-lane.
__global__ __launch_bounds__(256, 4) void k_attn(const short* __restrict__ qf,
                                                 const short* __restrict__ kf,
                                                 const short* __restrict__ vf,
                                                 const float* __restrict__ x,
                                                 const float* __restrict__ peh,
                                                 const float* __restrict__ pew,
                                                 float* __restrict__ out) {
    __shared__ float phS[64], pwS[64], redS[4];
    int t = threadIdx.x;
    if (t < 64) {
        phS[t] = (t < 63) ? peh[t] * LOG2E : -1e30f;
        pwS[t] = (t < 63) ? pew[t] * LOG2E : -1e30f;
    }

    int bh = blockIdx.x;
    int wid = t >> 6, lane = t & 63;
    int li = lane & 15, hl = lane >> 4;
    int it = blockIdx.y * 4 + wid;

    const short* qfh = qf + (size_t)bh * 64 * 256;
    const short* kfh = kf + (size_t)bh * 64 * 256;
    const short* vfh = vf + (size_t)bh * 64 * 256;

    // --- kmax scan: wave covers 16 j-tiles ---
    float knm = 0.f;
    #pragma unroll 4
    for (int jt2 = wid * 16; jt2 < wid * 16 + 16; ++jt2) {
        bf4 kb = *(const bf4*)(kfh + ((size_t)jt2 * 64 + lane) * 4);
        float s = 0.f;
        #pragma unroll
        for (int jj = 0; jj < 4; ++jj) {
            float kv = bf2f(kb[jj]);
            s = fmaf(kv, kv, s);
        }
        s += __shfl_xor(s, 16);
        s += __shfl_xor(s, 32);
        knm = fmaxf(knm, s);
    }
    knm = fmaxf(knm, __shfl_xor(knm, 1));
    knm = fmaxf(knm, __shfl_xor(knm, 2));
    knm = fmaxf(knm, __shfl_xor(knm, 4));
    knm = fmaxf(knm, __shfl_xor(knm, 8));
    if (lane == 0) redS[wid] = knm;
    __syncthreads();
    float kmax = sqrtf(fmaxf(fmaxf(redS[0], redS[1]), fmaxf(redS[2], redS[3])));

    // --- bias max (wave-redundant reduce over the LDS tables) ---
    float mph = phS[lane], mpw = pwS[lane];
    #pragma unroll
    for (int off = 32; off >= 1; off >>= 1) {
        mph = fmaxf(mph, __shfl_xor(mph, off));
        mpw = fmaxf(mpw, __shfl_xor(mpw, off));
    }
    float biasmax = mph + mpw;

    // --- Q fragment + per-query bound ---
    bf4 qfr = *(const bf4*)(qfh + ((size_t)it * 64 + lane) * 4);
    float qn2 = 0.f;
    #pragma unroll
    for (int jj = 0; jj < 4; ++jj) {
        float qv = bf2f(qfr[jj]);
        qn2 = fmaf(qv, qv, qn2);
    }
    qn2 += __shfl_xor(qn2, 16);
    qn2 += __shfl_xor(qn2, 32);
    float Mi = sqrtf(qn2) * kmax + biasmax;

    // --- w-bias minus bound, fixed over the key loop ---
    int wi = ((it & 1) << 4) | li;
    float pwm[2][4];
    #pragma unroll
    for (int jp = 0; jp < 2; ++jp)
        #pragma unroll
        for (int r = 0; r < 4; ++r)
            pwm[jp][r] = pwS[wi + 31 - ((jp << 4) + 4 * hl + r)] - Mi;

    int hq = it >> 1;  // i>>5, constant per tile
    f32x4 oacc = (f32x4)0.f;
    float lsum = 0.f;

    bf4 kA[4], vA[4], kB[4], vB[4];
    auto loadf = [&](bf4* kb, bf4* vb, int ch) {
        const short* kp = kfh + ((size_t)ch * 4 * 64 + lane) * 4;
        const short* vp = vfh + ((size_t)ch * 4 * 64 + lane) * 4;
        #pragma unroll
        for (int jt = 0; jt < 4; ++jt) {
            kb[jt] = *(const bf4*)(kp + jt * 256);
            vb[jt] = *(const bf4*)(vp + jt * 256);
        }
    };
    auto compute = [&](bf4* kb, bf4* vb, int ch) {
        float ph0 = phS[hq + 31 - 2 * ch];
        float ph1 = phS[hq + 30 - 2 * ch];
        f32x4 s[4];
        #pragma unroll
        for (int jt = 0; jt < 4; ++jt) {
            float ph = (jt < 2) ? ph0 : ph1;
            f32x4 c;
            #pragma unroll
            for (int r = 0; r < 4; ++r) c[r] = pwm[jt & 1][r] + ph;
            s[jt] = mfma16(kb[jt], qfr, c);
        }
        #pragma unroll
        for (int jt = 0; jt < 4; ++jt) {
            #pragma unroll
            for (int r = 0; r < 4; ++r) {
                s[jt][r] = exp2f(s[jt][r]);
                lsum += s[jt][r];
            }
        }
        #pragma unroll
        for (int jt = 0; jt < 4; ++jt) {
            unsigned lo = __builtin_amdgcn_perm(fbits(s[jt][1]), fbits(s[jt][0]), 0x07060302u);
            unsigned hi = __builtin_amdgcn_perm(fbits(s[jt][3]), fbits(s[jt][2]), 0x07060302u);
            unsigned pk[2] = {lo, hi};
            bf4 pf;
            __builtin_memcpy(&pf, pk, 8);
            oacc = mfma16(vb[jt], pf, oacc);
        }
    };

    loadf(kA, vA, 0);
    #pragma unroll 1
    for (int ch = 0; ch < 16; ch += 2) {
        loadf(kB, vB, ch + 1);
        compute(kA, vA, ch);
        if (ch + 2 < 16) loadf(kA, vA, ch + 2);
        compute(kB, vB, ch + 1);
    }

    lsum += __shfl_xor(lsum, 16);
    lsum += __shfl_xor(lsum, 32);
    float rl = 1.0f / lsum;

    int b = bh >> 3, h = bh & 7;
    size_t base = (size_t)b * (CC * NN) + (size_t)h * KD * NN;
    int i = it * 16 + li;
    #pragma unroll
    for (int r = 0; r < 4; ++r) {
        int d = 4 * hl + r;
        size_t g = base + (size_t)d * NN + i;
        out[g] = x[g] + oacc[r] * rl;
    }
}

extern "C" void kernel_launch(void* const* d_in, const int* in_sizes, int n_in,
                              void* d_out, int out_size, void* d_ws, size_t ws_size,
                              hipStream_t stream) {
    const float* x     = (const float*)d_in[0];
    const float* gamma = (const float*)d_in[1];
    const float* beta  = (const float*)d_in[2];
    const float* wq    = (const float*)d_in[3];
    const float* wk    = (const float*)d_in[4];
    const float* wv    = (const float*)d_in[5];
    const float* peh   = (const float*)d_in[6];
    const float* pew   = (const float*)d_in[7];
    float* out = (float*)d_out;
    float* ws  = (float*)d_ws;

    float* ss = ws;                                  // 256 f32
    float* a  = ws + 256;                            // 1M f32 activations
    short* qf = (short*)(ws + 256 + BB * CC * NN);   // 1M bf16 frags each
    short* kf = qf + (1 << 20);
    short* vf = kf + (1 << 20);

    k_bnstats<<<128, 256, 0, stream>>>(x, gamma, beta, ss);
    k_act<<<256, 256, 0, stream>>>(x, ss, a);
    k_proj<<<dim3(16, 6, 8), 256, 0, stream>>>(a, wq, wk, wv, qf, kf, vf);
    k_attn<<<dim3(64, 16), 256, 0, stream>>>(qf, kf, vf, x, peh, pew, out);
}

// Round 5
// 51.354 us; speedup vs baseline: 5.2177x; 1.0793x over previous
//
#include <hip/hip_runtime.h>
#include <hip/hip_bf16.h>
#include <math.h>

typedef short bf4 __attribute__((ext_vector_type(4)));
typedef float f32x4 __attribute__((ext_vector_type(4)));

constexpr int CC  = 128;
constexpr int NH  = 8;
constexpr int KD  = 16;
constexpr int BB  = 8;
constexpr int NN  = 1024;
constexpr int BHW = BB * NN;
constexpr float LOG2E = 1.44269504088896340736f;

static __device__ __forceinline__ short f2bf(float x) {
    __hip_bfloat16 b = __float2bfloat16(x);
    short s;
    __builtin_memcpy(&s, &b, 2);
    return s;
}
static __device__ __forceinline__ float bf2f(short s) {
    unsigned u = ((unsigned)(unsigned short)s) << 16;
    float f;
    __builtin_memcpy(&f, &u, 4);
    return f;
}
static __device__ __forceinline__ unsigned fbits(float x) {
    unsigned u;
    __builtin_memcpy(&u, &x, 4);
    return u;
}

static __device__ __forceinline__ f32x4 mfma16(bf4 a, bf4 b, f32x4 c) {
#if __has_builtin(__builtin_amdgcn_mfma_f32_16x16x16bf16_1k)
    return __builtin_amdgcn_mfma_f32_16x16x16bf16_1k(a, b, c, 0, 0, 0);
#else
    f32x4 d;
    asm volatile("v_mfma_f32_16x16x16_bf16 %0, %1, %2, %3"
                 : "=&v"(d) : "v"(a), "v"(b), "v"(c));
    return d;
#endif
}

// ---------------- K1: BN stats + W->bf16 fragment prep (fused) ----------
// blocks 0..127: per-channel mean/var -> scale/shift.
// blocks 128..175: convert wq/wk/wv to bf16 A-fragments (q pre-scaled).
__global__ __launch_bounds__(256) void k_prep(const float* __restrict__ x,
                                              const float* __restrict__ gamma,
                                              const float* __restrict__ beta,
                                              const float* __restrict__ wq,
                                              const float* __restrict__ wk,
                                              const float* __restrict__ wv,
                                              float* __restrict__ ss,
                                              short* __restrict__ wf) {
    int t = threadIdx.x;
    if (blockIdx.x < 128) {
        int c = blockIdx.x;
        float s1 = 0.f, s2 = 0.f;
        #pragma unroll
        for (int k = 0; k < 8; ++k) {
            int e = t + 256 * k;
            int b = e >> 8, off = e & 255;
            float4 v = ((const float4*)(x + ((size_t)b * CC + c) * NN))[off];
            s1 += v.x + v.y + v.z + v.w;
            s2 += v.x * v.x + v.y * v.y + v.z * v.z + v.w * v.w;
        }
        #pragma unroll
        for (int off = 32; off >= 1; off >>= 1) {
            s1 += __shfl_xor(s1, off);
            s2 += __shfl_xor(s2, off);
        }
        __shared__ float r1[4], r2[4];
        int wid = t >> 6, lane = t & 63;
        if (lane == 0) { r1[wid] = s1; r2[wid] = s2; }
        __syncthreads();
        if (t == 0) {
            float a1 = r1[0] + r1[1] + r1[2] + r1[3];
            float a2 = r2[0] + r2[1] + r2[2] + r2[3];
            float mean = a1 / (float)BHW;
            float var  = a2 / (float)BHW - mean * mean;
            float rstd = rsqrtf(var + 1e-5f);
            float sc = rstd * gamma[c];
            ss[c]      = sc;
            ss[CC + c] = beta[c] - mean * sc;
        }
    } else {
        // Wf[((p*8+mt)*8+ct)*64 + lane][jj] = W_p[mt*16+li][ct*16+4*hl+jj]
        int s = (blockIdx.x - 128) * 256 + t;   // 0..12287
        int lane = s & 63, ct = (s >> 6) & 7, mt = (s >> 9) & 7, p = s >> 12;
        int hl = lane >> 4, li = lane & 15;
        const float* w = (p == 0) ? wq : (p == 1) ? wk : wv;
        float4 v = *(const float4*)(w + (size_t)(mt * 16 + li) * CC + ct * 16 + 4 * hl);
        float sc = (p == 0) ? 0.25f * LOG2E : 1.0f;
        bf4 r;
        r[0] = f2bf(v.x * sc); r[1] = f2bf(v.y * sc);
        r[2] = f2bf(v.z * sc); r[3] = f2bf(v.w * sc);
        *(bf4*)&wf[(size_t)s * 4] = r;
    }
}

// ---------------- K2: fused BN+GELU + QKV projection via MFMA -----------
// grid (64, 8): x = 16-pixel tile, y = batch. block 256 (4 waves).
// Per block: M=384 (q|k|v outs), N=16 pixels, K=128 channels.
// Wave w owns m-tiles 6w..6w+5. Q/K D-tiles are already in the attention
// fragment layout; V tiles get a 16x16 LDS-bounce transpose.
__global__ __launch_bounds__(256) void k_proj(const float* __restrict__ x,
                                              const float* __restrict__ ss,
                                              const short* __restrict__ wf,
                                              short* __restrict__ qf,
                                              short* __restrict__ kf,
                                              short* __restrict__ vf) {
    __shared__ float xS[128][20];     // x tile (fp32), aliased later as vScr
    __shared__ float ssS[256];
    __shared__ short afS[8][256];     // act B-frags [ct][lane*4]
    int it = blockIdx.x, b = blockIdx.y;
    int t = threadIdx.x;
    ssS[t] = ss[t];
    const float* xb = x + (size_t)b * CC * NN + it * 16;
    #pragma unroll
    for (int k = 0; k < 2; ++k) {
        int s = t + 256 * k;
        int r = s >> 2, cf = s & 3;
        float4 v = *(const float4*)(xb + (size_t)r * NN + cf * 4);
        *(float4*)&xS[r][cf * 4] = v;
    }
    __syncthreads();
    #pragma unroll
    for (int k = 0; k < 2; ++k) {
        int s = t + 256 * k;
        int ct = s >> 6, ln = s & 63;
        int hl_ = ln >> 4, li_ = ln & 15;
        int c0 = ct * 16 + 4 * hl_;
        bf4 r;
        #pragma unroll
        for (int jj = 0; jj < 4; ++jj) {
            int c = c0 + jj;
            float v = xS[c][li_] * ssS[c] + ssS[128 + c];
            v = 0.5f * v * (1.0f + erff(v * 0.70710678f));
            r[jj] = f2bf(v);
        }
        *(bf4*)&afS[ct][ln * 4] = r;
    }
    __syncthreads();

    int wid = t >> 6, lane = t & 63;
    int hl = lane >> 4, li = lane & 15;
    f32x4 acc[6];
    #pragma unroll
    for (int e = 0; e < 6; ++e) acc[e] = (f32x4)0.f;

    #pragma unroll
    for (int ct = 0; ct < 8; ++ct) {
        bf4 af = *(const bf4*)&afS[ct][lane * 4];
        #pragma unroll
        for (int e = 0; e < 6; ++e) {
            int mtp = wid * 6 + e, p = mtp >> 3, mt = mtp & 7;
            bf4 wfr = *(const bf4*)(wf + ((size_t)((p * 8 + mt) * 8 + ct) * 64 + lane) * 4);
            acc[e] = mfma16(wfr, af, acc[e]);
        }
    }

    // Q/K epilogue: D lane(hl,li) holds [d=4hl+r][i=it*16+li] == frag layout.
    int bq = b * 8;
    #pragma unroll
    for (int e = 0; e < 6; ++e) {
        int mtp = wid * 6 + e, p = mtp >> 3, h = mtp & 7;
        if (p < 2) {
            short* dst = (p == 0) ? qf : kf;
            bf4 r;
            #pragma unroll
            for (int jr = 0; jr < 4; ++jr) r[jr] = f2bf(acc[e][jr]);
            *(bf4*)&dst[(((size_t)(bq + h) * 64 + it) * 64 + lane) * 4] = r;
        }
    }
    // V epilogue: transpose each 16x16 tile via LDS (uniform barriers).
    float* vScr = &xS[0][0];   // [8][16][17] fp32, reuses xS space
    __syncthreads();
    #pragma unroll
    for (int e = 0; e < 6; ++e) {
        int mtp = wid * 6 + e;
        if (mtp >= 16) {
            int h = mtp & 7;
            #pragma unroll
            for (int r = 0; r < 4; ++r)
                vScr[(h * 16 + 4 * hl + r) * 17 + li] = acc[e][r];
        }
    }
    __syncthreads();
    #pragma unroll
    for (int hh = wid * 2; hh < wid * 2 + 2; ++hh) {
        bf4 r;
        #pragma unroll
        for (int jj = 0; jj < 4; ++jj)
            r[jj] = f2bf(vScr[(hh * 16 + li) * 17 + 4 * hl + jj]);
        *(bf4*)&vf[(((size_t)(bq + hh) * 64 + it) * 64 + lane) * 4] = r;
    }
}

// ---------------- K3: one-pass attention via Cauchy-Schwarz bound ------
// grid (64, 16): x = b*8+h, y = 4 i-tiles. block = 256 (4 waves), wave owns
// one 16-query i-tile. M_i = |q_i| * max_j|k_j| + max(bias) >= true row max,
// so softmax is one pass: P = exp2(s - M_i), l accumulated per-lane.
__global__ __launch_bounds__(256, 4) void k_attn(const short* __restrict__ qf,
                                                 const short* __restrict__ kf,
                                                 const short* __restrict__ vf,
                                                 const float* __restrict__ x,
                                                 const float* __restrict__ peh,
                                                 const float* __restrict__ pew,
                                                 float* __restrict__ out) {
    __shared__ float phS[64], pwS[64], redS[4];
    int t = threadIdx.x;
    if (t < 64) {
        phS[t] = (t < 63) ? peh[t] * LOG2E : -1e30f;
        pwS[t] = (t < 63) ? pew[t] * LOG2E : -1e30f;
    }

    int bh = blockIdx.x;
    int wid = t >> 6, lane = t & 63;
    int li = lane & 15, hl = lane >> 4;
    int it = blockIdx.y * 4 + wid;

    const short* qfh = qf + (size_t)bh * 64 * 256;
    const short* kfh = kf + (size_t)bh * 64 * 256;
    const short* vfh = vf + (size_t)bh * 64 * 256;

    // --- kmax scan: wave covers 16 j-tiles ---
    float knm = 0.f;
    #pragma unroll 4
    for (int jt2 = wid * 16; jt2 < wid * 16 + 16; ++jt2) {
        bf4 kb = *(const bf4*)(kfh + ((size_t)jt2 * 64 + lane) * 4);
        float s = 0.f;
        #pragma unroll
        for (int jj = 0; jj < 4; ++jj) {
            float kv = bf2f(kb[jj]);
            s = fmaf(kv, kv, s);
        }
        s += __shfl_xor(s, 16);
        s += __shfl_xor(s, 32);
        knm = fmaxf(knm, s);
    }
    knm = fmaxf(knm, __shfl_xor(knm, 1));
    knm = fmaxf(knm, __shfl_xor(knm, 2));
    knm = fmaxf(knm, __shfl_xor(knm, 4));
    knm = fmaxf(knm, __shfl_xor(knm, 8));
    if (lane == 0) redS[wid] = knm;
    __syncthreads();
    float kmax = sqrtf(fmaxf(fmaxf(redS[0], redS[1]), fmaxf(redS[2], redS[3])));

    // --- bias max (wave-redundant reduce over the LDS tables) ---
    float mph = phS[lane], mpw = pwS[lane];
    #pragma unroll
    for (int off = 32; off >= 1; off >>= 1) {
        mph = fmaxf(mph, __shfl_xor(mph, off));
        mpw = fmaxf(mpw, __shfl_xor(mpw, off));
    }
    float biasmax = mph + mpw;

    // --- Q fragment + per-query bound ---
    bf4 qfr = *(const bf4*)(qfh + ((size_t)it * 64 + lane) * 4);
    float qn2 = 0.f;
    #pragma unroll
    for (int jj = 0; jj < 4; ++jj) {
        float qv = bf2f(qfr[jj]);
        qn2 = fmaf(qv, qv, qn2);
    }
    qn2 += __shfl_xor(qn2, 16);
    qn2 += __shfl_xor(qn2, 32);
    float Mi = sqrtf(qn2) * kmax + biasmax;

    // --- w-bias minus bound, fixed over the key loop ---
    int wi = ((it & 1) << 4) | li;
    float pwm[2][4];
    #pragma unroll
    for (int jp = 0; jp < 2; ++jp)
        #pragma unroll
        for (int r = 0; r < 4; ++r)
            pwm[jp][r] = pwS[wi + 31 - ((jp << 4) + 4 * hl + r)] - Mi;

    int hq = it >> 1;  // i>>5, constant per tile
    f32x4 oacc = (f32x4)0.f;
    float lsum = 0.f;

    bf4 kA[4], vA[4], kB[4], vB[4];
    auto loadf = [&](bf4* kb, bf4* vb, int ch) {
        const short* kp = kfh + ((size_t)ch * 4 * 64 + lane) * 4;
        const short* vp = vfh + ((size_t)ch * 4 * 64 + lane) * 4;
        #pragma unroll
        for (int jt = 0; jt < 4; ++jt) {
            kb[jt] = *(const bf4*)(kp + jt * 256);
            vb[jt] = *(const bf4*)(vp + jt * 256);
        }
    };
    auto compute = [&](bf4* kb, bf4* vb, int ch) {
        float ph0 = phS[hq + 31 - 2 * ch];
        float ph1 = phS[hq + 30 - 2 * ch];
        f32x4 s[4];
        #pragma unroll
        for (int jt = 0; jt < 4; ++jt) {
            float ph = (jt < 2) ? ph0 : ph1;
            f32x4 c;
            #pragma unroll
            for (int r = 0; r < 4; ++r) c[r] = pwm[jt & 1][r] + ph;
            s[jt] = mfma16(kb[jt], qfr, c);
        }
        #pragma unroll
        for (int jt = 0; jt < 4; ++jt) {
            #pragma unroll
            for (int r = 0; r < 4; ++r) {
                s[jt][r] = exp2f(s[jt][r]);
                lsum += s[jt][r];
            }
        }
        #pragma unroll
        for (int jt = 0; jt < 4; ++jt) {
            unsigned lo = __builtin_amdgcn_perm(fbits(s[jt][1]), fbits(s[jt][0]), 0x07060302u);
            unsigned hi = __builtin_amdgcn_perm(fbits(s[jt][3]), fbits(s[jt][2]), 0x07060302u);
            unsigned pk[2] = {lo, hi};
            bf4 pf;
            __builtin_memcpy(&pf, pk, 8);
            oacc = mfma16(vb[jt], pf, oacc);
        }
    };

    loadf(kA, vA, 0);
    #pragma unroll 1
    for (int ch = 0; ch < 16; ch += 2) {
        loadf(kB, vB, ch + 1);
        compute(kA, vA, ch);
        if (ch + 2 < 16) loadf(kA, vA, ch + 2);
        compute(kB, vB, ch + 1);
    }

    lsum += __shfl_xor(lsum, 16);
    lsum += __shfl_xor(lsum, 32);
    float rl = 1.0f / lsum;

    int b = bh >> 3, h = bh & 7;
    size_t base = (size_t)b * (CC * NN) + (size_t)h * KD * NN;
    int i = it * 16 + li;
    #pragma unroll
    for (int r = 0; r < 4; ++r) {
        int d = 4 * hl + r;
        size_t g = base + (size_t)d * NN + i;
        out[g] = x[g] + oacc[r] * rl;
    }
}

extern "C" void kernel_launch(void* const* d_in, const int* in_sizes, int n_in,
                              void* d_out, int out_size, void* d_ws, size_t ws_size,
                              hipStream_t stream) {
    const float* x     = (const float*)d_in[0];
    const float* gamma = (const float*)d_in[1];
    const float* beta  = (const float*)d_in[2];
    const float* wq    = (const float*)d_in[3];
    const float* wk    = (const float*)d_in[4];
    const float* wv    = (const float*)d_in[5];
    const float* peh   = (const float*)d_in[6];
    const float* pew   = (const float*)d_in[7];
    float* out = (float*)d_out;
    float* ws  = (float*)d_ws;

    float* ss = ws;                          // 256 f32
    short* wf = (short*)(ws + 256);          // 49152 shorts: W bf16 frags
    short* qf = wf + 49152;                  // 1M shorts each (2 MB)
    short* kf = qf + (1 << 20);
    short* vf = kf + (1 << 20);

    k_prep<<<176, 256, 0, stream>>>(x, gamma, beta, wq, wk, wv, ss, wf);
    k_proj<<<dim3(64, 8), 256, 0, stream>>>(x, ss, wf, qf, kf, vf);
    k_attn<<<dim3(64, 16), 256, 0, stream>>>(qf, kf, vf, x, peh, pew, out);
}

// Round 6
// 42.799 us; speedup vs baseline: 6.2606x; 1.1999x over previous
//
#include <hip/hip_runtime.h>
#include <hip/hip_bf16.h>
#include <math.h>

typedef short bf4 __attribute__((ext_vector_type(4)));
typedef float f32x4 __attribute__((ext_vector_type(4)));

constexpr int CC  = 128;
constexpr int NH  = 8;
constexpr int KD  = 16;
constexpr int BB  = 8;
constexpr int NN  = 1024;
constexpr int BHW = BB * NN;
constexpr float LOG2E = 1.44269504088896340736f;

static __device__ __forceinline__ short f2bf(float x) {
    __hip_bfloat16 b = __float2bfloat16(x);
    short s;
    __builtin_memcpy(&s, &b, 2);
    return s;
}
static __device__ __forceinline__ float bf2f(short s) {
    unsigned u = ((unsigned)(unsigned short)s) << 16;
    float f;
    __builtin_memcpy(&f, &u, 4);
    return f;
}
static __device__ __forceinline__ unsigned fbits(float x) {
    unsigned u;
    __builtin_memcpy(&u, &x, 4);
    return u;
}

static __device__ __forceinline__ f32x4 mfma16(bf4 a, bf4 b, f32x4 c) {
#if __has_builtin(__builtin_amdgcn_mfma_f32_16x16x16bf16_1k)
    return __builtin_amdgcn_mfma_f32_16x16x16bf16_1k(a, b, c, 0, 0, 0);
#else
    f32x4 d;
    asm volatile("v_mfma_f32_16x16x16_bf16 %0, %1, %2, %3"
                 : "=&v"(d) : "v"(a), "v"(b), "v"(c));
    return d;
#endif
}

// ---------------- K1: BN stats + W->bf16 fragment prep (fused) ----------
__global__ __launch_bounds__(256) void k_prep(const float* __restrict__ x,
                                              const float* __restrict__ gamma,
                                              const float* __restrict__ beta,
                                              const float* __restrict__ wq,
                                              const float* __restrict__ wk,
                                              const float* __restrict__ wv,
                                              float* __restrict__ ss,
                                              short* __restrict__ wf) {
    int t = threadIdx.x;
    if (blockIdx.x < 128) {
        int c = blockIdx.x;
        float s1 = 0.f, s2 = 0.f;
        #pragma unroll
        for (int k = 0; k < 8; ++k) {
            int e = t + 256 * k;
            int b = e >> 8, off = e & 255;
            float4 v = ((const float4*)(x + ((size_t)b * CC + c) * NN))[off];
            s1 += v.x + v.y + v.z + v.w;
            s2 += v.x * v.x + v.y * v.y + v.z * v.z + v.w * v.w;
        }
        #pragma unroll
        for (int off = 32; off >= 1; off >>= 1) {
            s1 += __shfl_xor(s1, off);
            s2 += __shfl_xor(s2, off);
        }
        __shared__ float r1[4], r2[4];
        int wid = t >> 6, lane = t & 63;
        if (lane == 0) { r1[wid] = s1; r2[wid] = s2; }
        __syncthreads();
        if (t == 0) {
            float a1 = r1[0] + r1[1] + r1[2] + r1[3];
            float a2 = r2[0] + r2[1] + r2[2] + r2[3];
            float mean = a1 / (float)BHW;
            float var  = a2 / (float)BHW - mean * mean;
            float rstd = rsqrtf(var + 1e-5f);
            float sc = rstd * gamma[c];
            ss[c]      = sc;
            ss[CC + c] = beta[c] - mean * sc;
        }
    } else {
        // Wf[((p*8+mt)*8+ct)*64 + lane][jj] = W_p[mt*16+li][ct*16+4*hl+jj]
        int s = (blockIdx.x - 128) * 256 + t;   // 0..12287
        int lane = s & 63, ct = (s >> 6) & 7, mt = (s >> 9) & 7, p = s >> 12;
        int hl = lane >> 4, li = lane & 15;
        const float* w = (p == 0) ? wq : (p == 1) ? wk : wv;
        float4 v = *(const float4*)(w + (size_t)(mt * 16 + li) * CC + ct * 16 + 4 * hl);
        float sc = (p == 0) ? 0.25f * LOG2E : 1.0f;
        bf4 r;
        r[0] = f2bf(v.x * sc); r[1] = f2bf(v.y * sc);
        r[2] = f2bf(v.z * sc); r[3] = f2bf(v.w * sc);
        *(bf4*)&wf[(size_t)s * 4] = r;
    }
}

// ---------------- K2: fused BN+GELU + QKV projection via MFMA -----------
// grid (64, 8): x = 16-pixel tile, y = batch. block 512 (8 waves).
// Wave w owns m-tiles 3w..3w+2 of 24 (q:0-7, k:8-15, v:16-23).
__global__ __launch_bounds__(512) void k_proj(const float* __restrict__ x,
                                              const float* __restrict__ ss,
                                              const short* __restrict__ wf,
                                              short* __restrict__ qf,
                                              short* __restrict__ kf,
                                              short* __restrict__ vf) {
    __shared__ float xS[128][20];     // x tile (fp32), aliased later as vScr
    __shared__ float ssS[256];
    __shared__ short afS[8][256];     // act B-frags [ct][lane*4]
    int it = blockIdx.x, b = blockIdx.y;
    int t = threadIdx.x;
    if (t < 256) ssS[t] = ss[t];
    const float* xb = x + (size_t)b * CC * NN + it * 16;
    {
        int r = t >> 2, cf = t & 3;
        float4 v = *(const float4*)(xb + (size_t)r * NN + cf * 4);
        *(float4*)&xS[r][cf * 4] = v;
    }
    __syncthreads();
    {
        int ct = t >> 6, ln = t & 63;
        int hl_ = ln >> 4, li_ = ln & 15;
        int c0 = ct * 16 + 4 * hl_;
        bf4 r;
        #pragma unroll
        for (int jj = 0; jj < 4; ++jj) {
            int c = c0 + jj;
            float v = xS[c][li_] * ssS[c] + ssS[128 + c];
            v = 0.5f * v * (1.0f + erff(v * 0.70710678f));
            r[jj] = f2bf(v);
        }
        *(bf4*)&afS[ct][ln * 4] = r;
    }
    __syncthreads();

    int wid = t >> 6, lane = t & 63;
    int hl = lane >> 4, li = lane & 15;
    f32x4 acc[3];
    #pragma unroll
    for (int e = 0; e < 3; ++e) acc[e] = (f32x4)0.f;

    #pragma unroll
    for (int ct = 0; ct < 8; ++ct) {
        bf4 af = *(const bf4*)&afS[ct][lane * 4];
        #pragma unroll
        for (int e = 0; e < 3; ++e) {
            int mtp = wid * 3 + e, p = mtp >> 3, mt = mtp & 7;
            bf4 wfr = *(const bf4*)(wf + ((size_t)((p * 8 + mt) * 8 + ct) * 64 + lane) * 4);
            acc[e] = mfma16(wfr, af, acc[e]);
        }
    }

    // Q/K epilogue: D lane(hl,li) holds [d=4hl+r][i=it*16+li] == frag layout.
    int bq = b * 8;
    #pragma unroll
    for (int e = 0; e < 3; ++e) {
        int mtp = wid * 3 + e, p = mtp >> 3, h = mtp & 7;
        if (p < 2) {
            short* dst = (p == 0) ? qf : kf;
            bf4 r;
            #pragma unroll
            for (int jr = 0; jr < 4; ++jr) r[jr] = f2bf(acc[e][jr]);
            *(bf4*)&dst[(((size_t)(bq + h) * 64 + it) * 64 + lane) * 4] = r;
        }
    }
    // V epilogue: transpose each 16x16 tile via LDS (uniform barriers).
    float* vScr = &xS[0][0];   // [8][16][17] fp32, reuses xS space
    __syncthreads();
    #pragma unroll
    for (int e = 0; e < 3; ++e) {
        int mtp = wid * 3 + e;
        if (mtp >= 16) {
            int h = mtp & 7;
            #pragma unroll
            for (int r = 0; r < 4; ++r)
                vScr[(h * 16 + 4 * hl + r) * 17 + li] = acc[e][r];
        }
    }
    __syncthreads();
    {
        int hh = wid;  // 8 waves, 8 v-tiles
        bf4 r;
        #pragma unroll
        for (int jj = 0; jj < 4; ++jj)
            r[jj] = f2bf(vScr[(hh * 16 + li) * 17 + 4 * hl + jj]);
        *(bf4*)&vf[(((size_t)(bq + hh) * 64 + it) * 64 + lane) * 4] = r;
    }
}

// ---------------- K3: one-pass attention, K head staged in LDS ---------
// grid (64, 16): x = b*8+h, y = i-tile group. block = 256 (4 waves), wave
// owns one 16-query i-tile. K head (32 KB) staged to LDS once per block;
// V double-buffered via register prefetch. One-pass softmax with
// Cauchy-Schwarz bound M_i = |q_i|*max_j|k_j| + max(bias).
__global__ __launch_bounds__(256, 4) void k_attn(const short* __restrict__ qf,
                                                 const short* __restrict__ kf,
                                                 const short* __restrict__ vf,
                                                 const float* __restrict__ x,
                                                 const float* __restrict__ peh,
                                                 const float* __restrict__ pew,
                                                 float* __restrict__ out) {
    __shared__ short ldsK[16384];    // 32 KB: full K head, fragment-linear
    __shared__ float phS[64], pwS[64], redS[4];
    int t = threadIdx.x;
    int bh = blockIdx.x;

    const short* qfh = qf + (size_t)bh * 16384;
    const short* kfh = kf + (size_t)bh * 16384;
    const short* vfh = vf + (size_t)bh * 16384;

    #pragma unroll
    for (int k = 0; k < 8; ++k)
        ((int4*)ldsK)[t + 256 * k] = ((const int4*)kfh)[t + 256 * k];
    if (t < 64) {
        phS[t] = (t < 63) ? peh[t] * LOG2E : -1e30f;
        pwS[t] = (t < 63) ? pew[t] * LOG2E : -1e30f;
    }
    __syncthreads();

    int wid = t >> 6, lane = t & 63;
    int li = lane & 15, hl = lane >> 4;
    int it = blockIdx.y * 4 + wid;

    // --- kmax scan from LDS: wave covers 16 j-tiles ---
    float knm = 0.f;
    #pragma unroll 4
    for (int jt2 = wid * 16; jt2 < wid * 16 + 16; ++jt2) {
        bf4 kb = *(const bf4*)&ldsK[jt2 * 256 + lane * 4];
        float s = 0.f;
        #pragma unroll
        for (int jj = 0; jj < 4; ++jj) {
            float kv = bf2f(kb[jj]);
            s = fmaf(kv, kv, s);
        }
        s += __shfl_xor(s, 16);
        s += __shfl_xor(s, 32);
        knm = fmaxf(knm, s);
    }
    knm = fmaxf(knm, __shfl_xor(knm, 1));
    knm = fmaxf(knm, __shfl_xor(knm, 2));
    knm = fmaxf(knm, __shfl_xor(knm, 4));
    knm = fmaxf(knm, __shfl_xor(knm, 8));
    if (lane == 0) redS[wid] = knm;
    __syncthreads();
    float kmax = sqrtf(fmaxf(fmaxf(redS[0], redS[1]), fmaxf(redS[2], redS[3])));

    // --- bias max (wave-redundant reduce over the LDS tables) ---
    float mph = phS[lane], mpw = pwS[lane];
    #pragma unroll
    for (int off = 32; off >= 1; off >>= 1) {
        mph = fmaxf(mph, __shfl_xor(mph, off));
        mpw = fmaxf(mpw, __shfl_xor(mpw, off));
    }
    float biasmax = mph + mpw;

    // --- Q fragment + per-query bound ---
    bf4 qfr = *(const bf4*)(qfh + ((size_t)it * 64 + lane) * 4);
    float qn2 = 0.f;
    #pragma unroll
    for (int jj = 0; jj < 4; ++jj) {
        float qv = bf2f(qfr[jj]);
        qn2 = fmaf(qv, qv, qn2);
    }
    qn2 += __shfl_xor(qn2, 16);
    qn2 += __shfl_xor(qn2, 32);
    float Mi = sqrtf(qn2) * kmax + biasmax;

    // --- w-bias minus bound, fixed over the key loop ---
    int wi = ((it & 1) << 4) | li;
    float pwm[2][4];
    #pragma unroll
    for (int jp = 0; jp < 2; ++jp)
        #pragma unroll
        for (int r = 0; r < 4; ++r)
            pwm[jp][r] = pwS[wi + 31 - ((jp << 4) + 4 * hl + r)] - Mi;

    int hq = it >> 1;
    f32x4 oacc = (f32x4)0.f;
    float lsum = 0.f;

    bf4 vA[4], vB[4];
    auto loadV = [&](bf4* vb, int ch) {
        const short* vp = vfh + ((size_t)ch * 4 * 64 + lane) * 4;
        #pragma unroll
        for (int jt = 0; jt < 4; ++jt)
            vb[jt] = *(const bf4*)(vp + jt * 256);
    };
    auto compute = [&](bf4* vb, int ch) {
        float ph0 = phS[hq + 31 - 2 * ch];
        float ph1 = phS[hq + 30 - 2 * ch];
        f32x4 s[4];
        #pragma unroll
        for (int jt = 0; jt < 4; ++jt) {
            bf4 kb = *(const bf4*)&ldsK[(ch * 4 + jt) * 256 + lane * 4];
            float ph = (jt < 2) ? ph0 : ph1;
            f32x4 c;
            #pragma unroll
            for (int r = 0; r < 4; ++r) c[r] = pwm[jt & 1][r] + ph;
            s[jt] = mfma16(kb, qfr, c);
        }
        #pragma unroll
        for (int jt = 0; jt < 4; ++jt) {
            #pragma unroll
            for (int r = 0; r < 4; ++r) {
                s[jt][r] = exp2f(s[jt][r]);
                lsum += s[jt][r];
            }
        }
        #pragma unroll
        for (int jt = 0; jt < 4; ++jt) {
            unsigned lo = __builtin_amdgcn_perm(fbits(s[jt][1]), fbits(s[jt][0]), 0x07060302u);
            unsigned hi = __builtin_amdgcn_perm(fbits(s[jt][3]), fbits(s[jt][2]), 0x07060302u);
            unsigned pk[2] = {lo, hi};
            bf4 pf;
            __builtin_memcpy(&pf, pk, 8);
            oacc = mfma16(vb[jt], pf, oacc);
        }
    };

    loadV(vA, 0);
    #pragma unroll 1
    for (int ch = 0; ch < 16; ch += 2) {
        loadV(vB, ch + 1);
        compute(vA, ch);
        if (ch + 2 < 16) loadV(vA, ch + 2);
        compute(vB, ch + 1);
    }

    lsum += __shfl_xor(lsum, 16);
    lsum += __shfl_xor(lsum, 32);
    float rl = 1.0f / lsum;

    int b = bh >> 3, h = bh & 7;
    size_t base = (size_t)b * (CC * NN) + (size_t)h * KD * NN;
    int i = it * 16 + li;
    #pragma unroll
    for (int r = 0; r < 4; ++r) {
        int d = 4 * hl + r;
        size_t g = base + (size_t)d * NN + i;
        out[g] = x[g] + oacc[r] * rl;
    }
}

extern "C" void kernel_launch(void* const* d_in, const int* in_sizes, int n_in,
                              void* d_out, int out_size, void* d_ws, size_t ws_size,
                              hipStream_t stream) {
    const float* x     = (const float*)d_in[0];
    const float* gamma = (const float*)d_in[1];
    const float* beta  = (const float*)d_in[2];
    const float* wq    = (const float*)d_in[3];
    const float* wk    = (const float*)d_in[4];
    const float* wv    = (const float*)d_in[5];
    const float* peh   = (const float*)d_in[6];
    const float* pew   = (const float*)d_in[7];
    float* out = (float*)d_out;
    float* ws  = (float*)d_ws;

    float* ss = ws;                          // 256 f32
    short* wf = (short*)(ws + 256);          // 49152 shorts: W bf16 frags
    short* qf = wf + 49152;                  // 1M shorts each (2 MB)
    short* kf = qf + (1 << 20);
    short* vf = kf + (1 << 20);

    k_prep<<<176, 256, 0, stream>>>(x, gamma, beta, wq, wk, wv, ss, wf);
    k_proj<<<dim3(64, 8), 512, 0, stream>>>(x, ss, wf, qf, kf, vf);
    k_attn<<<dim3(64, 16), 256, 0, stream>>>(qf, kf, vf, x, peh, pew, out);
}